// Round 10
// baseline (496.101 us; speedup 1.0000x reference)
//
#include <hip/hip_runtime.h>
#include <hip/hip_bf16.h>

#define N_NODES 50000
#define N_EDGES 800000

#define SCAN_BS 256
#define SCAN_NB ((N_NODES + SCAN_BS - 1) / SCAN_BS)   // 196

// prep kernel block-range layout
#define PREP_CVT_NB   6250   // N*32 / 256 (uint2 groups of 4 floats)
#define PREP_DEG_NB   3125   // E / 256
#define PREP_WCAT_NB  192    // 384*128 / 256
#define PREP_TP_NB    64     // 128*128 / 256 (and 64*256/256)
#define PREP_NB (PREP_CVT_NB + PREP_DEG_NB + PREP_WCAT_NB + 3 * PREP_TP_NB)

typedef __attribute__((ext_vector_type(8))) short bf16x8;
typedef __attribute__((ext_vector_type(4))) float f32x4;

__device__ __forceinline__ ushort f2bf(float f) {
    unsigned u = __float_as_uint(f);
    return (ushort)((u + 0x7fffu + ((u >> 16) & 1u)) >> 16);
}
__device__ __forceinline__ float bf2f(ushort u) {
    return __uint_as_float(((unsigned)u) << 16);
}

// ---------------------------------------------------------------------------
// Fused prep: x->bf16 (XCD-sliced layout) | degree hist | weight packs
// xb_sliced: [4][N][32] bf16  (slice s = channels 32s..32s+31)
// ---------------------------------------------------------------------------
__global__ __launch_bounds__(256)
void prep_kernel(const float* __restrict__ x, uint2* __restrict__ xbs4,
                 const int* __restrict__ edst, int* __restrict__ hist,
                 const float* __restrict__ Ws1, const float* __restrict__ Wm21,
                 const float* __restrict__ Wm1,
                 const float* __restrict__ bs1, const float* __restrict__ bm21,
                 const float* __restrict__ bm1,
                 ushort* __restrict__ Wcat_t, float* __restrict__ bcat,
                 const float* __restrict__ Ws2, ushort* __restrict__ Ws2t,
                 const float* __restrict__ Wm22, ushort* __restrict__ Wm22t,
                 const float* __restrict__ Wfc, ushort* __restrict__ Wfct,
                 int* __restrict__ row_ptr) {
    const int bid = blockIdx.x;
    const int t = threadIdx.x;
    if (bid < PREP_CVT_NB) {
        int i = bid * 256 + t;                 // [0, N*32): 4-float group
        float4 v = *(const float4*)&x[(size_t)i * 4];
        uint2 o;
        o.x = (uint)f2bf(v.x) | ((uint)f2bf(v.y) << 16);
        o.y = (uint)f2bf(v.z) | ((uint)f2bf(v.w) << 16);
        int node = i >> 5;
        int g = i & 31;                        // 4-ch group within 128-ch row
        int slice = g >> 3;                    // 0..3
        int wi = g & 7;                        // uint2 slot within 32-ch slice
        xbs4[((size_t)slice * N_NODES + node) * 8 + wi] = o;
    } else if (bid < PREP_CVT_NB + PREP_DEG_NB) {
        int e = (bid - PREP_CVT_NB) * 256 + t;
        atomicAdd(&hist[edst[e]], 1);
    } else if (bid < PREP_CVT_NB + PREP_DEG_NB + PREP_WCAT_NB) {
        int idx = (bid - PREP_CVT_NB - PREP_DEG_NB) * 256 + t;
        int c = idx >> 7, k = idx & 127;
        float v = (c < 128) ? Ws1[k * 128 + c]
                : (c < 256) ? Wm21[k * 128 + (c - 128)]
                            : Wm1[k * 128 + (c - 256)];
        Wcat_t[idx] = f2bf(v);
        if (idx < 384) {
            bcat[idx] = (idx < 128) ? bs1[idx] : (idx < 256) ? bm21[idx - 128] : bm1[idx - 256];
        }
        if (idx == 0) row_ptr[N_NODES] = N_EDGES;
    } else if (bid < PREP_CVT_NB + PREP_DEG_NB + PREP_WCAT_NB + PREP_TP_NB) {
        int idx = (bid - PREP_CVT_NB - PREP_DEG_NB - PREP_WCAT_NB) * 256 + t;
        int c = idx >> 7, k = idx & 127;
        Ws2t[idx] = f2bf(Ws2[(size_t)k * 128 + c]);
    } else if (bid < PREP_CVT_NB + PREP_DEG_NB + PREP_WCAT_NB + 2 * PREP_TP_NB) {
        int idx = (bid - PREP_CVT_NB - PREP_DEG_NB - PREP_WCAT_NB - PREP_TP_NB) * 256 + t;
        int c = idx >> 7, k = idx & 127;
        Wm22t[idx] = f2bf(Wm22[(size_t)k * 128 + c]);
    } else {
        int idx = (bid - PREP_CVT_NB - PREP_DEG_NB - PREP_WCAT_NB - 2 * PREP_TP_NB) * 256 + t;
        int c = idx >> 8, k = idx & 255;
        Wfct[idx] = f2bf(Wfc[(size_t)k * 64 + c]);
    }
}

// ---------------------------------------------------------------------------
// scan phase 1: per-block sums + dinv
// ---------------------------------------------------------------------------
__global__ __launch_bounds__(SCAN_BS)
void scan1_kernel(const int* __restrict__ hist, int* __restrict__ bsum,
                  float* __restrict__ dinv, int n) {
    __shared__ int s[SCAN_BS];
    int t = threadIdx.x;
    int i = blockIdx.x * SCAN_BS + t;
    int v = (i < n) ? hist[i] : 0;
    if (i < n) dinv[i] = rsqrtf((float)(v + 1));
    s[t] = v;
    __syncthreads();
#pragma unroll
    for (int off = SCAN_BS / 2; off > 0; off >>= 1) {
        if (t < off) s[t] += s[t + off];
        __syncthreads();
    }
    if (t == 0) bsum[blockIdx.x] = s[0];
}

// ---------------------------------------------------------------------------
// scan phase 2: own bsum-prefix + local exclusive scan -> row_ptr & cursor
// ---------------------------------------------------------------------------
__global__ __launch_bounds__(SCAN_BS)
void scan3_kernel(const int* __restrict__ hist, const int* __restrict__ bsum,
                  int* __restrict__ row_ptr, int* __restrict__ cursor, int n) {
    __shared__ int s[SCAN_BS];
    __shared__ int pre_s;
    int t = threadIdx.x;
    int b = blockIdx.x;
    int p = 0;
    for (int j = t; j < b; j += SCAN_BS) p += bsum[j];
    s[t] = p;
    __syncthreads();
#pragma unroll
    for (int off = SCAN_BS / 2; off > 0; off >>= 1) {
        if (t < off) s[t] += s[t + off];
        __syncthreads();
    }
    if (t == 0) pre_s = s[0];
    __syncthreads();
    const int pre = pre_s;
    __syncthreads();
    int i = b * SCAN_BS + t;
    int v = (i < n) ? hist[i] : 0;
    s[t] = v;
    __syncthreads();
#pragma unroll
    for (int off = 1; off < SCAN_BS; off <<= 1) {
        int tmp = (t >= off) ? s[t - off] : 0;
        __syncthreads();
        s[t] += tmp;
        __syncthreads();
    }
    if (i < n) {
        int ex = s[t] - v + pre;
        row_ptr[i] = ex;
        cursor[i]  = ex;
    }
}

__global__ void fill_kernel(const int* __restrict__ src, const int* __restrict__ dst, int E,
                            int* __restrict__ cursor, int2* __restrict__ edge_data,
                            const float* __restrict__ dinv) {
    int e = blockIdx.x * blockDim.x + threadIdx.x;
    if (e < E) {
        int d = dst[e];
        int s = src[e];
        int pos = atomicAdd(&cursor[d], 1);
        edge_data[pos] = make_int2(s, __float_as_int(dinv[s]));
    }
}

// ---------------------------------------------------------------------------
// XCD-sliced aggregation. Source Xs is [NSLICES][n][32] bf16 (64B rows).
// slice = blockIdx % NSLICES -> with round-robin blockIdx->XCD dispatch each
// XCD gathers from a single 3.2MB slice that fits its 4MB L2.
// One wave per (node, slice): 16 edge slots x 4 lanes/row; 4 nodes/wave.
// Output Y is node-major (ldy), fp32 accumulate -> bf16.
// ---------------------------------------------------------------------------
template<int NSLICES>
__global__ __launch_bounds__(256)
void agg_sliced(const ushort* __restrict__ Xs,
                ushort* __restrict__ Y, int ldy,
                const int* __restrict__ row_ptr,
                const int2* __restrict__ edge_data,
                const float* __restrict__ dinv, int n) {
    const int slice = blockIdx.x % NSLICES;
    const int grp   = blockIdx.x / NSLICES;
    const int wave  = threadIdx.x >> 6;
    const int lane  = threadIdx.x & 63;
    const int chunk = lane & 3;      // 16B chunk within 64B row
    const int slot  = lane >> 2;     // 0..15
    const ushort* X = Xs + (size_t)slice * n * 32;

#pragma unroll 1
    for (int nd = 0; nd < 4; ++nd) {
        const int node = grp * 16 + wave * 4 + nd;
        if (node >= n) break;
        const float di = dinv[node];
        float acc[8] = {0.f, 0.f, 0.f, 0.f, 0.f, 0.f, 0.f, 0.f};

        auto fma_row = [&](uint4 v, float w) {
            acc[0] = fmaf(w, __uint_as_float(v.x << 16), acc[0]);
            acc[1] = fmaf(w, __uint_as_float(v.x & 0xffff0000u), acc[1]);
            acc[2] = fmaf(w, __uint_as_float(v.y << 16), acc[2]);
            acc[3] = fmaf(w, __uint_as_float(v.y & 0xffff0000u), acc[3]);
            acc[4] = fmaf(w, __uint_as_float(v.z << 16), acc[4]);
            acc[5] = fmaf(w, __uint_as_float(v.z & 0xffff0000u), acc[5]);
            acc[6] = fmaf(w, __uint_as_float(v.w << 16), acc[6]);
            acc[7] = fmaf(w, __uint_as_float(v.w & 0xffff0000u), acc[7]);
        };

        if (slot == 0) {
            uint4 v = *(const uint4*)&X[(size_t)node * 32 + chunk * 8];
            fma_row(v, di * di);
        }
        const int e0 = row_ptr[node], e1 = row_ptr[node + 1];
        int e = e0 + slot;
        for (; e + 16 < e1; e += 32) {
            const int2 d0 = edge_data[e];
            const int2 d1 = edge_data[e + 16];
            const uint4 v0 = *(const uint4*)&X[(size_t)d0.x * 32 + chunk * 8];
            const uint4 v1 = *(const uint4*)&X[(size_t)d1.x * 32 + chunk * 8];
            fma_row(v0, di * __int_as_float(d0.y));
            fma_row(v1, di * __int_as_float(d1.y));
        }
        if (e < e1) {
            const int2 d0 = edge_data[e];
            const uint4 v0 = *(const uint4*)&X[(size_t)d0.x * 32 + chunk * 8];
            fma_row(v0, di * __int_as_float(d0.y));
        }
        // reduce across 16 slots (lane strides 4,8,16,32)
#pragma unroll
        for (int j = 0; j < 8; ++j) {
            acc[j] += __shfl_xor(acc[j], 4);
            acc[j] += __shfl_xor(acc[j], 8);
            acc[j] += __shfl_xor(acc[j], 16);
            acc[j] += __shfl_xor(acc[j], 32);
        }
        if (slot == 0) {
            uint4 o;
            o.x = (uint)f2bf(acc[0]) | ((uint)f2bf(acc[1]) << 16);
            o.y = (uint)f2bf(acc[2]) | ((uint)f2bf(acc[3]) << 16);
            o.z = (uint)f2bf(acc[4]) | ((uint)f2bf(acc[5]) << 16);
            o.w = (uint)f2bf(acc[6]) | ((uint)f2bf(acc[7]) << 16);
            *(uint4*)&Y[(size_t)node * ldy + slice * 32 + chunk * 8] = o;
        }
    }
}

// ---------------------------------------------------------------------------
// bf16 MFMA GEMM, K=128. BM=128, BN=128, 256 threads. (layer-1 fused GEMM)
// Epilogue writes cols 0:256 to XCD-sliced catA [8][N][32], cols 256:384 to
// node-major h1 [N][128].
// ---------------------------------------------------------------------------
__global__ __launch_bounds__(256)
void mfma_gemm_kernel(const ushort* __restrict__ A, int lda,
                      const ushort* __restrict__ Wt,
                      const float* __restrict__ bias,
                      ushort* __restrict__ catA, ushort* __restrict__ h1, int M) {
    __shared__ char Asmem[128 * 272];
    const int tid = threadIdx.x;
    const int lane = tid & 63;
    const int w = tid >> 6;
    const int rb = blockIdx.x * 128;
    const int cb = blockIdx.y * 128;

    {
        const int rowbase = tid >> 4;
        const int seg = tid & 15;
#pragma unroll
        for (int it = 0; it < 8; ++it) {
            int row = it * 16 + rowbase;
            uint4 v = make_uint4(0u, 0u, 0u, 0u);
            int r = rb + row;
            if (r < M) v = *(const uint4*)&A[(size_t)r * lda + seg * 8];
            *(uint4*)&Asmem[row * 272 + seg * 16] = v;
        }
    }
    __syncthreads();

    f32x4 acc[2][8];
#pragma unroll
    for (int i = 0; i < 2; ++i)
#pragma unroll
        for (int j = 0; j < 8; ++j) acc[i][j] = (f32x4){0.f, 0.f, 0.f, 0.f};

    const int arow0 = w * 32 + (lane & 15);
    const int kq = (lane >> 4) * 8;
    const int ccol = lane & 15;
#pragma unroll
    for (int ks = 0; ks < 4; ++ks) {
        const int k0 = ks * 32;
        const bf16x8 a0 = *(const bf16x8*)&Asmem[arow0 * 272 + (k0 + kq) * 2];
        const bf16x8 a1 = *(const bf16x8*)&Asmem[(arow0 + 16) * 272 + (k0 + kq) * 2];
#pragma unroll
        for (int ct = 0; ct < 8; ++ct) {
            const bf16x8 b = *(const bf16x8*)&Wt[(size_t)(cb + ct * 16 + ccol) * 128 + k0 + kq];
            acc[0][ct] = __builtin_amdgcn_mfma_f32_16x16x32_bf16(a0, b, acc[0][ct], 0, 0, 0);
            acc[1][ct] = __builtin_amdgcn_mfma_f32_16x16x32_bf16(a1, b, acc[1][ct], 0, 0, 0);
        }
    }

    const int rowq = (lane >> 4) * 4;
#pragma unroll
    for (int rt = 0; rt < 2; ++rt) {
#pragma unroll
        for (int ct = 0; ct < 8; ++ct) {
            const int col = cb + ct * 16 + ccol;
#pragma unroll
            for (int r = 0; r < 4; ++r) {
                const int row = rb + w * 32 + rt * 16 + rowq + r;
                if (row >= M) continue;
                float v = fmaxf(acc[rt][ct][r] + bias[col], 0.f);
                ushort bv = f2bf(v);
                if (col < 256)
                    catA[((size_t)(col >> 5) * N_NODES + row) * 32 + (col & 31)] = bv;
                else
                    h1[(size_t)row * 128 + (col - 256)] = bv;
            }
        }
    }
}

// ---------------------------------------------------------------------------
// Fused layer-2 + attention + fc (unchanged except h1 is node-major [N][128]).
// ---------------------------------------------------------------------------
__global__ __launch_bounds__(512, 4)
void gemm2fc_kernel(const ushort* __restrict__ bufB,
                    const ushort* __restrict__ Ws2t, const float* __restrict__ bs2,
                    const ushort* __restrict__ Wm22t, const float* __restrict__ bm22,
                    const ushort* __restrict__ h1buf,
                    const float* __restrict__ Watt, const float* __restrict__ batt,
                    const ushort* __restrict__ Wfct, const float* __restrict__ bfc,
                    float* __restrict__ Y, int M) {
    __shared__ __align__(16) char smem[69632];
    const int tid = threadIdx.x;
    const int rb = blockIdx.x * 128;

    {
        const int seg = tid & 15;
        const int rowbase = tid >> 4;
#pragma unroll
        for (int it = 0; it < 8; ++it) {
            int idx = it * 32 + rowbase;
            int region = idx >> 7;
            int row = idx & 127;
            int r = rb + row;
            uint4 v = make_uint4(0u, 0u, 0u, 0u);
            if (r < M) v = *(const uint4*)&bufB[(size_t)r * 256 + region * 128 + seg * 8];
            *(uint4*)&smem[region * 34816 + row * 272 + seg * 16] = v;
        }
    }
    __syncthreads();

    const int w = tid >> 6;
    const int lane = tid & 63;
    const int branch = w >> 2;
    const int wl = w & 3;
    const char* Areg = smem + branch * 34816;
    const ushort* Wt = branch ? Wm22t : Ws2t;
    const float* bias = branch ? bm22 : bs2;

    f32x4 acc[2][8];
#pragma unroll
    for (int i = 0; i < 2; ++i)
#pragma unroll
        for (int j = 0; j < 8; ++j) acc[i][j] = (f32x4){0.f, 0.f, 0.f, 0.f};

    const int arow0 = wl * 32 + (lane & 15);
    const int kq = (lane >> 4) * 8;
    const int ccol = lane & 15;
#pragma unroll
    for (int ks = 0; ks < 4; ++ks) {
        const int k0 = ks * 32;
        const bf16x8 a0 = *(const bf16x8*)&Areg[arow0 * 272 + (k0 + kq) * 2];
        const bf16x8 a1 = *(const bf16x8*)&Areg[(arow0 + 16) * 272 + (k0 + kq) * 2];
#pragma unroll
        for (int ct = 0; ct < 8; ++ct) {
            const bf16x8 b = *(const bf16x8*)&Wt[(size_t)(ct * 16 + ccol) * 128 + k0 + kq];
            acc[0][ct] = __builtin_amdgcn_mfma_f32_16x16x32_bf16(a0, b, acc[0][ct], 0, 0, 0);
            acc[1][ct] = __builtin_amdgcn_mfma_f32_16x16x32_bf16(a1, b, acc[1][ct], 0, 0, 0);
        }
    }

#pragma unroll
    for (int rt = 0; rt < 2; ++rt)
#pragma unroll
        for (int ct = 0; ct < 8; ++ct) {
            const float bcol = bias[ct * 16 + ccol];
#pragma unroll
            for (int r = 0; r < 4; ++r)
                acc[rt][ct][r] = fmaxf(acc[rt][ct][r] + bcol, 0.f);
        }

    const int quad = lane >> 4;
    if (branch == 1) {
        float wv[8];
#pragma unroll
        for (int ct = 0; ct < 8; ++ct) wv[ct] = Watt[ct * 16 + ccol];
        const float ba = batt[0];
#pragma unroll
        for (int rt = 0; rt < 2; ++rt) {
#pragma unroll
            for (int r = 0; r < 4; ++r) {
                const int row0 = rb + wl * 32 + rt * 16 + quad * 4 + r;
                const int rowc = (row0 < M) ? row0 : (M - 1);
                const ushort* h1row = &h1buf[(size_t)rowc * 128];
                float bp = 0.f, ap = 0.f;
#pragma unroll
                for (int ct = 0; ct < 8; ++ct) {
                    bp += acc[rt][ct][r] * wv[ct];
                    ap += bf2f(h1row[ct * 16 + ccol]) * wv[ct];
                }
#pragma unroll
                for (int off = 1; off < 16; off <<= 1) {
                    bp += __shfl_xor(bp, off);
                    ap += __shfl_xor(ap, off);
                }
                const float a = ap + ba, b = bp + ba;
                const float m = fmaxf(a, b);
                const float ea = __expf(a - m), eb = __expf(b - m);
                const float inv = 1.f / (ea + eb);
                const float wa = ea * inv, wb = eb * inv;
#pragma unroll
                for (int ct = 0; ct < 8; ++ct) {
                    const float h1 = bf2f(h1row[ct * 16 + ccol]);
                    acc[rt][ct][r] = fmaf(wa, h1, wb * acc[rt][ct][r]);
                }
            }
        }
    }
    __syncthreads();

#pragma unroll
    for (int rt = 0; rt < 2; ++rt) {
#pragma unroll
        for (int ct = 0; ct < 8; ++ct) {
            const int col = branch * 128 + ct * 16 + ccol;
#pragma unroll
            for (int r = 0; r < 4; ++r) {
                const int row = wl * 32 + rt * 16 + quad * 4 + r;
                *(ushort*)&smem[row * 528 + col * 2] = f2bf(acc[rt][ct][r]);
            }
        }
    }
    __syncthreads();

    f32x4 fcacc[4];
#pragma unroll
    for (int j = 0; j < 4; ++j) fcacc[j] = (f32x4){0.f, 0.f, 0.f, 0.f};
    const int frow = w * 16 + (lane & 15);
#pragma unroll
    for (int ks = 0; ks < 8; ++ks) {
        const int k0 = ks * 32;
        const bf16x8 a = *(const bf16x8*)&smem[frow * 528 + (k0 + kq) * 2];
#pragma unroll
        for (int ct = 0; ct < 4; ++ct) {
            const bf16x8 b = *(const bf16x8*)&Wfct[(size_t)(ct * 16 + ccol) * 256 + k0 + kq];
            fcacc[ct] = __builtin_amdgcn_mfma_f32_16x16x32_bf16(a, b, fcacc[ct], 0, 0, 0);
        }
    }
#pragma unroll
    for (int ct = 0; ct < 4; ++ct) {
        const int col = ct * 16 + ccol;
        const float bcol = bfc[col];
#pragma unroll
        for (int r = 0; r < 4; ++r) {
            const int row = rb + w * 16 + quad * 4 + r;
            if (row < M) Y[(size_t)row * 64 + col] = fcacc[ct][r] + bcol;
        }
    }
}

// ---------------------------------------------------------------------------
extern "C" void kernel_launch(void* const* d_in, const int* in_sizes, int n_in,
                              void* d_out, int out_size, void* d_ws, size_t ws_size,
                              hipStream_t stream) {
    const int N = N_NODES, E = N_EDGES;
    const float* x     = (const float*)d_in[0];
    const int*   ei    = (const int*)d_in[1];
    const int*   esrc  = ei;
    const int*   edst  = ei + E;
    const float* W_s1  = (const float*)d_in[2];
    const float* b_s1  = (const float*)d_in[3];
    const float* W_s2  = (const float*)d_in[4];
    const float* b_s2  = (const float*)d_in[5];
    const float* W_m1  = (const float*)d_in[6];
    const float* b_m1  = (const float*)d_in[7];
    const float* W_m21 = (const float*)d_in[8];
    const float* b_m21 = (const float*)d_in[9];
    const float* W_m22 = (const float*)d_in[10];
    const float* b_m22 = (const float*)d_in[11];
    const float* W_att = (const float*)d_in[12];
    const float* b_att = (const float*)d_in[13];
    const float* W_fc  = (const float*)d_in[14];
    const float* b_fc  = (const float*)d_in[15];
    float* out = (float*)d_out;

    char* base = (char*)d_ws;
    size_t off = 0;
    auto take = [&](size_t nbytes) -> void* {
        void* p = base + off;
        off += (nbytes + 255) & ~(size_t)255;
        return p;
    };
    int*    hist      = (int*)take((size_t)N * 4);
    int*    cursor    = (int*)take((size_t)N * 4);
    int*    row_ptr   = (int*)take((size_t)(N + 1) * 4);
    int*    bsum      = (int*)take((size_t)SCAN_NB * 4);
    int2*   edge_data = (int2*)take((size_t)E * 8);
    float*  dinv      = (float*)take((size_t)N * 4);
    ushort* xbs       = (ushort*)take((size_t)N * 128 * 2);   // [4][N][32]
    ushort* agg_x     = (ushort*)take((size_t)N * 128 * 2);   // node-major
    ushort* catA      = (ushort*)take((size_t)N * 256 * 2);   // [8][N][32]
    ushort* h1buf     = (ushort*)take((size_t)N * 128 * 2);   // node-major
    ushort* bufB      = (ushort*)take((size_t)N * 256 * 2);   // node-major
    ushort* Wcat_t    = (ushort*)take((size_t)384 * 128 * 2);
    ushort* Ws2_t     = (ushort*)take((size_t)128 * 128 * 2);
    ushort* Wm22_t    = (ushort*)take((size_t)128 * 128 * 2);
    ushort* Wfc_t     = (ushort*)take((size_t)64 * 256 * 2);
    float*  bcat      = (float*)take((size_t)384 * 4);

    // 1. zero hist
    hipMemsetAsync(hist, 0, (size_t)N * 4, stream);
    // 2. fused prep
    prep_kernel<<<PREP_NB, 256, 0, stream>>>(x, (uint2*)xbs, edst, hist,
                                             W_s1, W_m21, W_m1, b_s1, b_m21, b_m1,
                                             Wcat_t, bcat, W_s2, Ws2_t, W_m22, Wm22_t,
                                             W_fc, Wfc_t, row_ptr);
    // 3-4. scan
    scan1_kernel<<<SCAN_NB, SCAN_BS, 0, stream>>>(hist, bsum, dinv, N);
    scan3_kernel<<<SCAN_NB, SCAN_BS, 0, stream>>>(hist, bsum, row_ptr, cursor, N);
    // 5. fill CSR
    fill_kernel<<<(E + 255) / 256, 256, 0, stream>>>(esrc, edst, E, cursor, edge_data, dinv);

    const int NGRP = (N + 15) / 16;   // 3125
    // 6. layer-1 aggregation (4 slices x 32ch), out node-major agg_x
    agg_sliced<4><<<NGRP * 4, 256, 0, stream>>>(xbs, agg_x, 128, row_ptr, edge_data, dinv, N);
    // 7. fused layer-1 GEMM -> catA (sliced) + h1 (node-major)
    dim3 gm384((N + 127) / 128, 3);
    mfma_gemm_kernel<<<gm384, 256, 0, stream>>>(agg_x, 128, Wcat_t, bcat, catA, h1buf, N);
    // 8. layer-2 aggregation (8 slices x 32ch), out node-major bufB
    agg_sliced<8><<<NGRP * 8, 256, 0, stream>>>(catA, bufB, 256, row_ptr, edge_data, dinv, N);
    // 9. fused layer-2 GEMMs + attention + fc -> d_out
    gemm2fc_kernel<<<(N + 127) / 128, 512, 0, stream>>>(bufB, Ws2_t, b_s2, Wm22_t, b_m22,
                                                        h1buf, W_att, b_att, Wfc_t, b_fc, out, N);
}

// Round 11
// 443.896 us; speedup vs baseline: 1.1176x; 1.1176x over previous
//
#include <hip/hip_runtime.h>
#include <hip/hip_bf16.h>

#define N_NODES 50000
#define N_EDGES 800000

#define SCAN_BS 256
#define SCAN_NB ((N_NODES + SCAN_BS - 1) / SCAN_BS)   // 196

// prep kernel block-range layout
#define PREP_CVT_NB   6250   // N*128/4 / 256
#define PREP_DEG_NB   3125   // E / 256
#define PREP_WCAT_NB  192    // 384*128 / 256
#define PREP_TP_NB    64     // 128*128 / 256 (and 64*256/256)
#define PREP_NB (PREP_CVT_NB + PREP_DEG_NB + PREP_WCAT_NB + 3 * PREP_TP_NB)

typedef __attribute__((ext_vector_type(8))) short bf16x8;
typedef __attribute__((ext_vector_type(4))) float f32x4;

__device__ __forceinline__ ushort f2bf(float f) {
    unsigned u = __float_as_uint(f);
    return (ushort)((u + 0x7fffu + ((u >> 16) & 1u)) >> 16);
}
__device__ __forceinline__ float bf2f(ushort u) {
    return __uint_as_float(((unsigned)u) << 16);
}

// ---------------------------------------------------------------------------
// Fused prep: x->bf16 cvt | degree histogram | weight packs | row_ptr[N]=E
// ---------------------------------------------------------------------------
__global__ __launch_bounds__(256)
void prep_kernel(const float* __restrict__ x, uint2* __restrict__ xb4,
                 const int* __restrict__ edst, int* __restrict__ hist,
                 const float* __restrict__ Ws1, const float* __restrict__ Wm21,
                 const float* __restrict__ Wm1,
                 const float* __restrict__ bs1, const float* __restrict__ bm21,
                 const float* __restrict__ bm1,
                 ushort* __restrict__ Wcat_t, float* __restrict__ bcat,
                 const float* __restrict__ Ws2, ushort* __restrict__ Ws2t,
                 const float* __restrict__ Wm22, ushort* __restrict__ Wm22t,
                 const float* __restrict__ Wfc, ushort* __restrict__ Wfct,
                 int* __restrict__ row_ptr) {
    const int bid = blockIdx.x;
    const int t = threadIdx.x;
    if (bid < PREP_CVT_NB) {
        int i = bid * 256 + t;
        float4 v = *(const float4*)&x[(size_t)i * 4];
        uint2 o;
        o.x = (uint)f2bf(v.x) | ((uint)f2bf(v.y) << 16);
        o.y = (uint)f2bf(v.z) | ((uint)f2bf(v.w) << 16);
        xb4[i] = o;
    } else if (bid < PREP_CVT_NB + PREP_DEG_NB) {
        int e = (bid - PREP_CVT_NB) * 256 + t;
        atomicAdd(&hist[edst[e]], 1);
    } else if (bid < PREP_CVT_NB + PREP_DEG_NB + PREP_WCAT_NB) {
        int idx = (bid - PREP_CVT_NB - PREP_DEG_NB) * 256 + t;
        int c = idx >> 7, k = idx & 127;
        float v = (c < 128) ? Ws1[k * 128 + c]
                : (c < 256) ? Wm21[k * 128 + (c - 128)]
                            : Wm1[k * 128 + (c - 256)];
        Wcat_t[idx] = f2bf(v);
        if (idx < 384) {
            bcat[idx] = (idx < 128) ? bs1[idx] : (idx < 256) ? bm21[idx - 128] : bm1[idx - 256];
        }
        if (idx == 0) row_ptr[N_NODES] = N_EDGES;
    } else if (bid < PREP_CVT_NB + PREP_DEG_NB + PREP_WCAT_NB + PREP_TP_NB) {
        int idx = (bid - PREP_CVT_NB - PREP_DEG_NB - PREP_WCAT_NB) * 256 + t;
        int c = idx >> 7, k = idx & 127;
        Ws2t[idx] = f2bf(Ws2[(size_t)k * 128 + c]);
    } else if (bid < PREP_CVT_NB + PREP_DEG_NB + PREP_WCAT_NB + 2 * PREP_TP_NB) {
        int idx = (bid - PREP_CVT_NB - PREP_DEG_NB - PREP_WCAT_NB - PREP_TP_NB) * 256 + t;
        int c = idx >> 7, k = idx & 127;
        Wm22t[idx] = f2bf(Wm22[(size_t)k * 128 + c]);
    } else {
        int idx = (bid - PREP_CVT_NB - PREP_DEG_NB - PREP_WCAT_NB - 2 * PREP_TP_NB) * 256 + t;
        int c = idx >> 8, k = idx & 255;
        Wfct[idx] = f2bf(Wfc[(size_t)k * 64 + c]);
    }
}

// ---------------------------------------------------------------------------
// scan phase 1: per-block sums of hist + dinv = rsqrt(deg+1)
// ---------------------------------------------------------------------------
__global__ __launch_bounds__(SCAN_BS)
void scan1_kernel(const int* __restrict__ hist, int* __restrict__ bsum,
                  float* __restrict__ dinv, int n) {
    __shared__ int s[SCAN_BS];
    int t = threadIdx.x;
    int i = blockIdx.x * SCAN_BS + t;
    int v = (i < n) ? hist[i] : 0;
    if (i < n) dinv[i] = rsqrtf((float)(v + 1));
    s[t] = v;
    __syncthreads();
#pragma unroll
    for (int off = SCAN_BS / 2; off > 0; off >>= 1) {
        if (t < off) s[t] += s[t + off];
        __syncthreads();
    }
    if (t == 0) bsum[blockIdx.x] = s[0];
}

// ---------------------------------------------------------------------------
// scan phase 2: own bsum-prefix + local exclusive scan -> row_ptr & cursor
// ---------------------------------------------------------------------------
__global__ __launch_bounds__(SCAN_BS)
void scan3_kernel(const int* __restrict__ hist, const int* __restrict__ bsum,
                  int* __restrict__ row_ptr, int* __restrict__ cursor, int n) {
    __shared__ int s[SCAN_BS];
    __shared__ int pre_s;
    int t = threadIdx.x;
    int b = blockIdx.x;
    int p = 0;
    for (int j = t; j < b; j += SCAN_BS) p += bsum[j];
    s[t] = p;
    __syncthreads();
#pragma unroll
    for (int off = SCAN_BS / 2; off > 0; off >>= 1) {
        if (t < off) s[t] += s[t + off];
        __syncthreads();
    }
    if (t == 0) pre_s = s[0];
    __syncthreads();
    const int pre = pre_s;
    __syncthreads();
    int i = b * SCAN_BS + t;
    int v = (i < n) ? hist[i] : 0;
    s[t] = v;
    __syncthreads();
#pragma unroll
    for (int off = 1; off < SCAN_BS; off <<= 1) {
        int tmp = (t >= off) ? s[t - off] : 0;
        __syncthreads();
        s[t] += tmp;
        __syncthreads();
    }
    if (i < n) {
        int ex = s[t] - v + pre;
        row_ptr[i] = ex;
        cursor[i]  = ex;
    }
}

__global__ void fill_kernel(const int* __restrict__ src, const int* __restrict__ dst, int E,
                            int* __restrict__ cursor, int2* __restrict__ edge_data,
                            const float* __restrict__ dinv) {
    int e = blockIdx.x * blockDim.x + threadIdx.x;
    if (e < E) {
        int d = dst[e];
        int s = src[e];
        int pos = atomicAdd(&cursor[d], 1);
        edge_data[pos] = make_int2(s, __float_as_int(dinv[s]));
    }
}

// ---------------------------------------------------------------------------
// bf16-gather aggregation, bf16 OUT. One wave per node, 4x unrolled edge loop.
// (used standalone for C=256 only)
// ---------------------------------------------------------------------------
template<int C>
__global__ __launch_bounds__(256)
void agg_bf16(const ushort* __restrict__ X, int ldx,
              ushort* __restrict__ Y, int ldy,
              const int* __restrict__ row_ptr,
              const int2* __restrict__ edge_data,
              const float* __restrict__ dinv, int n) {
    constexpr int CG = C / 8;       // lanes per row
    constexpr int SLOTS = 64 / CG;  // 2 for C=256
    const int wid = blockIdx.x * (blockDim.x >> 6) + (threadIdx.x >> 6);
    if (wid >= n) return;
    const int lane = threadIdx.x & 63;
    const int cg = lane & (CG - 1);
    const int slot = lane / CG;

    const float di = dinv[wid];
    float acc[8] = {0.f, 0.f, 0.f, 0.f, 0.f, 0.f, 0.f, 0.f};

    auto fma_row = [&](uint4 v, float w) {
        acc[0] = fmaf(w, __uint_as_float(v.x << 16), acc[0]);
        acc[1] = fmaf(w, __uint_as_float(v.x & 0xffff0000u), acc[1]);
        acc[2] = fmaf(w, __uint_as_float(v.y << 16), acc[2]);
        acc[3] = fmaf(w, __uint_as_float(v.y & 0xffff0000u), acc[3]);
        acc[4] = fmaf(w, __uint_as_float(v.z << 16), acc[4]);
        acc[5] = fmaf(w, __uint_as_float(v.z & 0xffff0000u), acc[5]);
        acc[6] = fmaf(w, __uint_as_float(v.w << 16), acc[6]);
        acc[7] = fmaf(w, __uint_as_float(v.w & 0xffff0000u), acc[7]);
    };

    if (slot == 0) {
        uint4 v = *(const uint4*)&X[(size_t)wid * ldx + cg * 8];
        fma_row(v, di * di);
    }
    const int e0 = row_ptr[wid], e1 = row_ptr[wid + 1];
    int e = e0 + slot;
    for (; e + 3 * SLOTS < e1; e += 4 * SLOTS) {
        const int2 d0 = edge_data[e];
        const int2 d1 = edge_data[e + SLOTS];
        const int2 d2 = edge_data[e + 2 * SLOTS];
        const int2 d3 = edge_data[e + 3 * SLOTS];
        const uint4 v0 = *(const uint4*)&X[(size_t)d0.x * ldx + cg * 8];
        const uint4 v1 = *(const uint4*)&X[(size_t)d1.x * ldx + cg * 8];
        const uint4 v2 = *(const uint4*)&X[(size_t)d2.x * ldx + cg * 8];
        const uint4 v3 = *(const uint4*)&X[(size_t)d3.x * ldx + cg * 8];
        fma_row(v0, di * __int_as_float(d0.y));
        fma_row(v1, di * __int_as_float(d1.y));
        fma_row(v2, di * __int_as_float(d2.y));
        fma_row(v3, di * __int_as_float(d3.y));
    }
    for (; e < e1; e += SLOTS) {
        const int2 d0 = edge_data[e];
        const uint4 v0 = *(const uint4*)&X[(size_t)d0.x * ldx + cg * 8];
        fma_row(v0, di * __int_as_float(d0.y));
    }
#pragma unroll
    for (int j = 0; j < 8; ++j) {
        if (SLOTS == 4) acc[j] += __shfl_xor(acc[j], 16);
        if (SLOTS >= 2) acc[j] += __shfl_xor(acc[j], 32);
    }
    if (slot == 0) {
        uint4 o;
        o.x = (uint)f2bf(acc[0]) | ((uint)f2bf(acc[1]) << 16);
        o.y = (uint)f2bf(acc[2]) | ((uint)f2bf(acc[3]) << 16);
        o.z = (uint)f2bf(acc[4]) | ((uint)f2bf(acc[5]) << 16);
        o.w = (uint)f2bf(acc[6]) | ((uint)f2bf(acc[7]) << 16);
        *(uint4*)&Y[(size_t)wid * ldy + cg * 8] = o;
    }
}

// ---------------------------------------------------------------------------
// Fused layer-1 aggregation + GEMM, barrier-free.
// Block = 64 rows x 4 waves; each wave aggregates exactly the 16 node-rows
// its own 16x16 MFMA tiles consume (wave-local LDS handoff, same-wave DS
// ordering => no __syncthreads). BN = 384 per wave (acc 24 x f32x4 = 96 VGPR).
// cat1 out: [N][384] bf16 = relu([agg] @ [W_s1|W_m21|W_m1] + bcat).
// ---------------------------------------------------------------------------
__global__ __launch_bounds__(256)
void agg_gemm1_kernel(const ushort* __restrict__ xb,       // [N][128]
                      const int* __restrict__ row_ptr,
                      const int2* __restrict__ edge_data,
                      const float* __restrict__ dinv,
                      const ushort* __restrict__ Wt,       // [384][128]
                      const float* __restrict__ bias,      // [384]
                      ushort* __restrict__ cat1, int n) {
    __shared__ __align__(16) char smem[64 * 272];
    const int tid = threadIdx.x;
    const int w = tid >> 6;
    const int lane = tid & 63;
    const int rb = blockIdx.x * 64;
    const int row0 = w * 16;
    char* myrows = smem + row0 * 272;

    // ---- phase 1: aggregate 16 nodes into this wave's LDS rows ----
    const int cg = lane & 15;      // 8-ch group (16B)
    const int slot = lane >> 4;    // 0..3
#pragma unroll 1
    for (int nd = 0; nd < 16; ++nd) {
        const int node = rb + row0 + nd;
        float acc[8] = {0.f, 0.f, 0.f, 0.f, 0.f, 0.f, 0.f, 0.f};
        auto fma_row = [&](uint4 v, float wgt) {
            acc[0] = fmaf(wgt, __uint_as_float(v.x << 16), acc[0]);
            acc[1] = fmaf(wgt, __uint_as_float(v.x & 0xffff0000u), acc[1]);
            acc[2] = fmaf(wgt, __uint_as_float(v.y << 16), acc[2]);
            acc[3] = fmaf(wgt, __uint_as_float(v.y & 0xffff0000u), acc[3]);
            acc[4] = fmaf(wgt, __uint_as_float(v.z << 16), acc[4]);
            acc[5] = fmaf(wgt, __uint_as_float(v.z & 0xffff0000u), acc[5]);
            acc[6] = fmaf(wgt, __uint_as_float(v.w << 16), acc[6]);
            acc[7] = fmaf(wgt, __uint_as_float(v.w & 0xffff0000u), acc[7]);
        };
        if (node < n) {
            const float di = dinv[node];
            if (slot == 0) {
                uint4 v = *(const uint4*)&xb[(size_t)node * 128 + cg * 8];
                fma_row(v, di * di);
            }
            const int e0 = row_ptr[node], e1 = row_ptr[node + 1];
            int e = e0 + slot;
            for (; e + 12 < e1; e += 16) {
                const int2 d0 = edge_data[e];
                const int2 d1 = edge_data[e + 4];
                const int2 d2 = edge_data[e + 8];
                const int2 d3 = edge_data[e + 12];
                const uint4 v0 = *(const uint4*)&xb[(size_t)d0.x * 128 + cg * 8];
                const uint4 v1 = *(const uint4*)&xb[(size_t)d1.x * 128 + cg * 8];
                const uint4 v2 = *(const uint4*)&xb[(size_t)d2.x * 128 + cg * 8];
                const uint4 v3 = *(const uint4*)&xb[(size_t)d3.x * 128 + cg * 8];
                fma_row(v0, di * __int_as_float(d0.y));
                fma_row(v1, di * __int_as_float(d1.y));
                fma_row(v2, di * __int_as_float(d2.y));
                fma_row(v3, di * __int_as_float(d3.y));
            }
            for (; e < e1; e += 4) {
                const int2 d0 = edge_data[e];
                const uint4 v0 = *(const uint4*)&xb[(size_t)d0.x * 128 + cg * 8];
                fma_row(v0, di * __int_as_float(d0.y));
            }
        }
#pragma unroll
        for (int j = 0; j < 8; ++j) {
            acc[j] += __shfl_xor(acc[j], 16);
            acc[j] += __shfl_xor(acc[j], 32);
        }
        if (slot == 0) {
            uint4 o;
            o.x = (uint)f2bf(acc[0]) | ((uint)f2bf(acc[1]) << 16);
            o.y = (uint)f2bf(acc[2]) | ((uint)f2bf(acc[3]) << 16);
            o.z = (uint)f2bf(acc[4]) | ((uint)f2bf(acc[5]) << 16);
            o.w = (uint)f2bf(acc[6]) | ((uint)f2bf(acc[7]) << 16);
            *(uint4*)&myrows[nd * 272 + cg * 16] = o;
        }
    }
    // same-wave ds_write -> ds_read is ordered; no barrier needed.

    // ---- phase 2: GEMM 16 rows x 384 cols, K=128 ----
    f32x4 acc2[24];
#pragma unroll
    for (int j = 0; j < 24; ++j) acc2[j] = (f32x4){0.f, 0.f, 0.f, 0.f};
    const int arow = lane & 15;
    const int kq = (lane >> 4) * 8;
    const int ccol = lane & 15;
#pragma unroll
    for (int ks = 0; ks < 4; ++ks) {
        const int k0 = ks * 32;
        const bf16x8 a = *(const bf16x8*)&myrows[arow * 272 + (k0 + kq) * 2];
#pragma unroll
        for (int ct = 0; ct < 24; ++ct) {
            const bf16x8 b = *(const bf16x8*)&Wt[(size_t)(ct * 16 + ccol) * 128 + k0 + kq];
            acc2[ct] = __builtin_amdgcn_mfma_f32_16x16x32_bf16(a, b, acc2[ct], 0, 0, 0);
        }
    }

    const int rowq = (lane >> 4) * 4;
#pragma unroll
    for (int ct = 0; ct < 24; ++ct) {
        const int col = ct * 16 + ccol;
        const float bcol = bias[col];
#pragma unroll
        for (int r = 0; r < 4; ++r) {
            const int row = rb + row0 + rowq + r;
            if (row < n)
                cat1[(size_t)row * 384 + col] = f2bf(fmaxf(acc2[ct][r] + bcol, 0.f));
        }
    }
}

// ---------------------------------------------------------------------------
// Fused layer-2 + attention + fc. 512 threads (8 waves) per 128-row tile.
// ---------------------------------------------------------------------------
__global__ __launch_bounds__(512, 4)
void gemm2fc_kernel(const ushort* __restrict__ bufB,
                    const ushort* __restrict__ Ws2t, const float* __restrict__ bs2,
                    const ushort* __restrict__ Wm22t, const float* __restrict__ bm22,
                    const ushort* __restrict__ cat1,
                    const float* __restrict__ Watt, const float* __restrict__ batt,
                    const ushort* __restrict__ Wfct, const float* __restrict__ bfc,
                    float* __restrict__ Y, int M) {
    __shared__ __align__(16) char smem[69632];
    const int tid = threadIdx.x;
    const int rb = blockIdx.x * 128;

    {
        const int seg = tid & 15;
        const int rowbase = tid >> 4;
#pragma unroll
        for (int it = 0; it < 8; ++it) {
            int idx = it * 32 + rowbase;
            int region = idx >> 7;
            int row = idx & 127;
            int r = rb + row;
            uint4 v = make_uint4(0u, 0u, 0u, 0u);
            if (r < M) v = *(const uint4*)&bufB[(size_t)r * 256 + region * 128 + seg * 8];
            *(uint4*)&smem[region * 34816 + row * 272 + seg * 16] = v;
        }
    }
    __syncthreads();

    const int w = tid >> 6;
    const int lane = tid & 63;
    const int branch = w >> 2;
    const int wl = w & 3;
    const char* Areg = smem + branch * 34816;
    const ushort* Wt = branch ? Wm22t : Ws2t;
    const float* bias = branch ? bm22 : bs2;

    f32x4 acc[2][8];
#pragma unroll
    for (int i = 0; i < 2; ++i)
#pragma unroll
        for (int j = 0; j < 8; ++j) acc[i][j] = (f32x4){0.f, 0.f, 0.f, 0.f};

    const int arow0 = wl * 32 + (lane & 15);
    const int kq = (lane >> 4) * 8;
    const int ccol = lane & 15;
#pragma unroll
    for (int ks = 0; ks < 4; ++ks) {
        const int k0 = ks * 32;
        const bf16x8 a0 = *(const bf16x8*)&Areg[arow0 * 272 + (k0 + kq) * 2];
        const bf16x8 a1 = *(const bf16x8*)&Areg[(arow0 + 16) * 272 + (k0 + kq) * 2];
#pragma unroll
        for (int ct = 0; ct < 8; ++ct) {
            const bf16x8 b = *(const bf16x8*)&Wt[(size_t)(ct * 16 + ccol) * 128 + k0 + kq];
            acc[0][ct] = __builtin_amdgcn_mfma_f32_16x16x32_bf16(a0, b, acc[0][ct], 0, 0, 0);
            acc[1][ct] = __builtin_amdgcn_mfma_f32_16x16x32_bf16(a1, b, acc[1][ct], 0, 0, 0);
        }
    }

#pragma unroll
    for (int rt = 0; rt < 2; ++rt)
#pragma unroll
        for (int ct = 0; ct < 8; ++ct) {
            const float bcol = bias[ct * 16 + ccol];
#pragma unroll
            for (int r = 0; r < 4; ++r)
                acc[rt][ct][r] = fmaxf(acc[rt][ct][r] + bcol, 0.f);
        }

    const int quad = lane >> 4;
    if (branch == 1) {
        float wv[8];
#pragma unroll
        for (int ct = 0; ct < 8; ++ct) wv[ct] = Watt[ct * 16 + ccol];
        const float ba = batt[0];
#pragma unroll
        for (int rt = 0; rt < 2; ++rt) {
#pragma unroll
            for (int r = 0; r < 4; ++r) {
                const int row0 = rb + wl * 32 + rt * 16 + quad * 4 + r;
                const int rowc = (row0 < M) ? row0 : (M - 1);
                const ushort* h1row = &cat1[(size_t)rowc * 384 + 256];
                float bp = 0.f, ap = 0.f;
#pragma unroll
                for (int ct = 0; ct < 8; ++ct) {
                    bp += acc[rt][ct][r] * wv[ct];
                    ap += bf2f(h1row[ct * 16 + ccol]) * wv[ct];
                }
#pragma unroll
                for (int off = 1; off < 16; off <<= 1) {
                    bp += __shfl_xor(bp, off);
                    ap += __shfl_xor(ap, off);
                }
                const float a = ap + ba, b = bp + ba;
                const float m = fmaxf(a, b);
                const float ea = __expf(a - m), eb = __expf(b - m);
                const float inv = 1.f / (ea + eb);
                const float wa = ea * inv, wb = eb * inv;
#pragma unroll
                for (int ct = 0; ct < 8; ++ct) {
                    const float h1 = bf2f(h1row[ct * 16 + ccol]);
                    acc[rt][ct][r] = fmaf(wa, h1, wb * acc[rt][ct][r]);
                }
            }
        }
    }
    __syncthreads();

#pragma unroll
    for (int rt = 0; rt < 2; ++rt) {
#pragma unroll
        for (int ct = 0; ct < 8; ++ct) {
            const int col = branch * 128 + ct * 16 + ccol;
#pragma unroll
            for (int r = 0; r < 4; ++r) {
                const int row = wl * 32 + rt * 16 + quad * 4 + r;
                *(ushort*)&smem[row * 528 + col * 2] = f2bf(acc[rt][ct][r]);
            }
        }
    }
    __syncthreads();

    f32x4 fcacc[4];
#pragma unroll
    for (int j = 0; j < 4; ++j) fcacc[j] = (f32x4){0.f, 0.f, 0.f, 0.f};
    const int frow = w * 16 + (lane & 15);
#pragma unroll
    for (int ks = 0; ks < 8; ++ks) {
        const int k0 = ks * 32;
        const bf16x8 a = *(const bf16x8*)&smem[frow * 528 + (k0 + kq) * 2];
#pragma unroll
        for (int ct = 0; ct < 4; ++ct) {
            const bf16x8 b = *(const bf16x8*)&Wfct[(size_t)(ct * 16 + ccol) * 256 + k0 + kq];
            fcacc[ct] = __builtin_amdgcn_mfma_f32_16x16x32_bf16(a, b, fcacc[ct], 0, 0, 0);
        }
    }
#pragma unroll
    for (int ct = 0; ct < 4; ++ct) {
        const int col = ct * 16 + ccol;
        const float bcol = bfc[col];
#pragma unroll
        for (int r = 0; r < 4; ++r) {
            const int row = rb + w * 16 + quad * 4 + r;
            if (row < M) Y[(size_t)row * 64 + col] = fcacc[ct][r] + bcol;
        }
    }
}

// ---------------------------------------------------------------------------
extern "C" void kernel_launch(void* const* d_in, const int* in_sizes, int n_in,
                              void* d_out, int out_size, void* d_ws, size_t ws_size,
                              hipStream_t stream) {
    const int N = N_NODES, E = N_EDGES;
    const float* x     = (const float*)d_in[0];
    const int*   ei    = (const int*)d_in[1];
    const int*   esrc  = ei;
    const int*   edst  = ei + E;
    const float* W_s1  = (const float*)d_in[2];
    const float* b_s1  = (const float*)d_in[3];
    const float* W_s2  = (const float*)d_in[4];
    const float* b_s2  = (const float*)d_in[5];
    const float* W_m1  = (const float*)d_in[6];
    const float* b_m1  = (const float*)d_in[7];
    const float* W_m21 = (const float*)d_in[8];
    const float* b_m21 = (const float*)d_in[9];
    const float* W_m22 = (const float*)d_in[10];
    const float* b_m22 = (const float*)d_in[11];
    const float* W_att = (const float*)d_in[12];
    const float* b_att = (const float*)d_in[13];
    const float* W_fc  = (const float*)d_in[14];
    const float* b_fc  = (const float*)d_in[15];
    float* out = (float*)d_out;

    char* base = (char*)d_ws;
    size_t off = 0;
    auto take = [&](size_t nbytes) -> void* {
        void* p = base + off;
        off += (nbytes + 255) & ~(size_t)255;
        return p;
    };
    int*    hist      = (int*)take((size_t)N * 4);
    int*    cursor    = (int*)take((size_t)N * 4);
    int*    row_ptr   = (int*)take((size_t)(N + 1) * 4);
    int*    bsum      = (int*)take((size_t)SCAN_NB * 4);
    int2*   edge_data = (int2*)take((size_t)E * 8);
    float*  dinv      = (float*)take((size_t)N * 4);
    ushort* xb        = (ushort*)take((size_t)N * 128 * 2);
    ushort* cat1      = (ushort*)take((size_t)N * 384 * 2);
    ushort* bufB      = (ushort*)take((size_t)N * 256 * 2);
    ushort* Wcat_t    = (ushort*)take((size_t)384 * 128 * 2);
    ushort* Ws2_t     = (ushort*)take((size_t)128 * 128 * 2);
    ushort* Wm22_t    = (ushort*)take((size_t)128 * 128 * 2);
    ushort* Wfc_t     = (ushort*)take((size_t)64 * 256 * 2);
    float*  bcat      = (float*)take((size_t)384 * 4);

    // 1. zero hist
    hipMemsetAsync(hist, 0, (size_t)N * 4, stream);
    // 2. fused prep
    prep_kernel<<<PREP_NB, 256, 0, stream>>>(x, (uint2*)xb, edst, hist,
                                             W_s1, W_m21, W_m1, b_s1, b_m21, b_m1,
                                             Wcat_t, bcat, W_s2, Ws2_t, W_m22, Wm22_t,
                                             W_fc, Wfc_t, row_ptr);
    // 3-4. scan
    scan1_kernel<<<SCAN_NB, SCAN_BS, 0, stream>>>(hist, bsum, dinv, N);
    scan3_kernel<<<SCAN_NB, SCAN_BS, 0, stream>>>(hist, bsum, row_ptr, cursor, N);
    // 5. fill CSR
    fill_kernel<<<(E + 255) / 256, 256, 0, stream>>>(esrc, edst, E, cursor, edge_data, dinv);

    // 6. fused layer-1 aggregation + GEMM -> cat1
    agg_gemm1_kernel<<<(N + 63) / 64, 256, 0, stream>>>(xb, row_ptr, edge_data, dinv,
                                                        Wcat_t, bcat, cat1, N);
    // 7. layer-2 aggregation of [h_s1 | h2a]
    agg_bf16<256><<<(N + 3) / 4, 256, 0, stream>>>(cat1, 384, bufB, 256, row_ptr, edge_data, dinv, N);
    // 8. fused layer-2 GEMMs + attention + fc -> d_out
    gemm2fc_kernel<<<(N + 127) / 128, 512, 0, stream>>>(bufB, Ws2_t, b_s2, Wm22_t, b_m22,
                                                        cat1, W_att, b_att, Wfc_t, b_fc, out, N);
}

// Round 12
// 345.777 us; speedup vs baseline: 1.4347x; 1.2838x over previous
//
#include <hip/hip_runtime.h>
#include <hip/hip_bf16.h>

#define N_NODES 50000
#define N_EDGES 800000

#define SCAN_BS 256
#define SCAN_NB ((N_NODES + SCAN_BS - 1) / SCAN_BS)   // 196

// prep kernel block-range layout
#define PREP_CVT_NB   6250   // N*128/4 / 256
#define PREP_DEG_NB   3125   // E / 256
#define PREP_WCAT_NB  192    // 384*128 / 256
#define PREP_TP_NB    64     // 128*128 / 256 (and 64*256/256)
#define PREP_NB (PREP_CVT_NB + PREP_DEG_NB + PREP_WCAT_NB + 3 * PREP_TP_NB)

typedef __attribute__((ext_vector_type(8))) short bf16x8;
typedef __attribute__((ext_vector_type(4))) float f32x4;

__device__ __forceinline__ ushort f2bf(float f) {
    unsigned u = __float_as_uint(f);
    return (ushort)((u + 0x7fffu + ((u >> 16) & 1u)) >> 16);
}
__device__ __forceinline__ float bf2f(ushort u) {
    return __uint_as_float(((unsigned)u) << 16);
}

// ---------------------------------------------------------------------------
// Fused prep: x->bf16 cvt | degree histogram + edge rank | weight packs
// rank[e] = this edge's arrival index within its dst bucket (coalesced write)
// ---------------------------------------------------------------------------
__global__ __launch_bounds__(256)
void prep_kernel(const float* __restrict__ x, uint2* __restrict__ xb4,
                 const int* __restrict__ edst, int* __restrict__ hist,
                 int* __restrict__ rank,
                 const float* __restrict__ Ws1, const float* __restrict__ Wm21,
                 const float* __restrict__ Wm1,
                 const float* __restrict__ bs1, const float* __restrict__ bm21,
                 const float* __restrict__ bm1,
                 ushort* __restrict__ Wcat_t, float* __restrict__ bcat,
                 const float* __restrict__ Ws2, ushort* __restrict__ Ws2t,
                 const float* __restrict__ Wm22, ushort* __restrict__ Wm22t,
                 const float* __restrict__ Wfc, ushort* __restrict__ Wfct,
                 int* __restrict__ row_ptr) {
    const int bid = blockIdx.x;
    const int t = threadIdx.x;
    if (bid < PREP_CVT_NB) {
        int i = bid * 256 + t;
        float4 v = *(const float4*)&x[(size_t)i * 4];
        uint2 o;
        o.x = (uint)f2bf(v.x) | ((uint)f2bf(v.y) << 16);
        o.y = (uint)f2bf(v.z) | ((uint)f2bf(v.w) << 16);
        xb4[i] = o;
    } else if (bid < PREP_CVT_NB + PREP_DEG_NB) {
        int e = (bid - PREP_CVT_NB) * 256 + t;
        rank[e] = atomicAdd(&hist[edst[e]], 1);
    } else if (bid < PREP_CVT_NB + PREP_DEG_NB + PREP_WCAT_NB) {
        int idx = (bid - PREP_CVT_NB - PREP_DEG_NB) * 256 + t;
        int c = idx >> 7, k = idx & 127;
        float v = (c < 128) ? Ws1[k * 128 + c]
                : (c < 256) ? Wm21[k * 128 + (c - 128)]
                            : Wm1[k * 128 + (c - 256)];
        Wcat_t[idx] = f2bf(v);
        if (idx < 384) {
            bcat[idx] = (idx < 128) ? bs1[idx] : (idx < 256) ? bm21[idx - 128] : bm1[idx - 256];
        }
        if (idx == 0) row_ptr[N_NODES] = N_EDGES;
    } else if (bid < PREP_CVT_NB + PREP_DEG_NB + PREP_WCAT_NB + PREP_TP_NB) {
        int idx = (bid - PREP_CVT_NB - PREP_DEG_NB - PREP_WCAT_NB) * 256 + t;
        int c = idx >> 7, k = idx & 127;
        Ws2t[idx] = f2bf(Ws2[(size_t)k * 128 + c]);
    } else if (bid < PREP_CVT_NB + PREP_DEG_NB + PREP_WCAT_NB + 2 * PREP_TP_NB) {
        int idx = (bid - PREP_CVT_NB - PREP_DEG_NB - PREP_WCAT_NB - PREP_TP_NB) * 256 + t;
        int c = idx >> 7, k = idx & 127;
        Wm22t[idx] = f2bf(Wm22[(size_t)k * 128 + c]);
    } else {
        int idx = (bid - PREP_CVT_NB - PREP_DEG_NB - PREP_WCAT_NB - 2 * PREP_TP_NB) * 256 + t;
        int c = idx >> 8, k = idx & 255;
        Wfct[idx] = f2bf(Wfc[(size_t)k * 64 + c]);
    }
}

// ---------------------------------------------------------------------------
// scan phase 1: per-block sums of hist + dinv = rsqrt(deg+1)
// ---------------------------------------------------------------------------
__global__ __launch_bounds__(SCAN_BS)
void scan1_kernel(const int* __restrict__ hist, int* __restrict__ bsum,
                  float* __restrict__ dinv, int n) {
    __shared__ int s[SCAN_BS];
    int t = threadIdx.x;
    int i = blockIdx.x * SCAN_BS + t;
    int v = (i < n) ? hist[i] : 0;
    if (i < n) dinv[i] = rsqrtf((float)(v + 1));
    s[t] = v;
    __syncthreads();
#pragma unroll
    for (int off = SCAN_BS / 2; off > 0; off >>= 1) {
        if (t < off) s[t] += s[t + off];
        __syncthreads();
    }
    if (t == 0) bsum[blockIdx.x] = s[0];
}

// ---------------------------------------------------------------------------
// scan phase 2: own bsum-prefix + local exclusive scan -> row_ptr
// ---------------------------------------------------------------------------
__global__ __launch_bounds__(SCAN_BS)
void scan3_kernel(const int* __restrict__ hist, const int* __restrict__ bsum,
                  int* __restrict__ row_ptr, int n) {
    __shared__ int s[SCAN_BS];
    __shared__ int pre_s;
    int t = threadIdx.x;
    int b = blockIdx.x;
    int p = 0;
    for (int j = t; j < b; j += SCAN_BS) p += bsum[j];
    s[t] = p;
    __syncthreads();
#pragma unroll
    for (int off = SCAN_BS / 2; off > 0; off >>= 1) {
        if (t < off) s[t] += s[t + off];
        __syncthreads();
    }
    if (t == 0) pre_s = s[0];
    __syncthreads();
    const int pre = pre_s;
    __syncthreads();
    int i = b * SCAN_BS + t;
    int v = (i < n) ? hist[i] : 0;
    s[t] = v;
    __syncthreads();
#pragma unroll
    for (int off = 1; off < SCAN_BS; off <<= 1) {
        int tmp = (t >= off) ? s[t - off] : 0;
        __syncthreads();
        s[t] += tmp;
        __syncthreads();
    }
    if (i < n) row_ptr[i] = s[t] - v + pre;
}

// ---------------------------------------------------------------------------
// fill: atomic-free scatter, pos = row_ptr[dst] + rank[e]
// ---------------------------------------------------------------------------
__global__ void fill_kernel(const int* __restrict__ src, const int* __restrict__ dst, int E,
                            const int* __restrict__ row_ptr, const int* __restrict__ rank,
                            int2* __restrict__ edge_data,
                            const float* __restrict__ dinv) {
    int e = blockIdx.x * blockDim.x + threadIdx.x;
    if (e < E) {
        int d = dst[e];
        int s = src[e];
        int pos = row_ptr[d] + rank[e];
        edge_data[pos] = make_int2(s, __float_as_int(dinv[s]));
    }
}

// ---------------------------------------------------------------------------
// bf16-gather aggregation, bf16 OUT. One wave per node, 4x unrolled edge loop.
// ---------------------------------------------------------------------------
template<int C>
__global__ __launch_bounds__(256)
void agg_bf16(const ushort* __restrict__ X, int ldx,
              ushort* __restrict__ Y, int ldy,
              const int* __restrict__ row_ptr,
              const int2* __restrict__ edge_data,
              const float* __restrict__ dinv, int n) {
    constexpr int CG = C / 8;       // lanes per row
    constexpr int SLOTS = 64 / CG;  // 2 for C=256, 4 for C=128
    const int wid = blockIdx.x * (blockDim.x >> 6) + (threadIdx.x >> 6);
    if (wid >= n) return;
    const int lane = threadIdx.x & 63;
    const int cg = lane & (CG - 1);
    const int slot = lane / CG;

    const float di = dinv[wid];
    float acc[8] = {0.f, 0.f, 0.f, 0.f, 0.f, 0.f, 0.f, 0.f};

    auto fma_row = [&](uint4 v, float w) {
        acc[0] = fmaf(w, __uint_as_float(v.x << 16), acc[0]);
        acc[1] = fmaf(w, __uint_as_float(v.x & 0xffff0000u), acc[1]);
        acc[2] = fmaf(w, __uint_as_float(v.y << 16), acc[2]);
        acc[3] = fmaf(w, __uint_as_float(v.y & 0xffff0000u), acc[3]);
        acc[4] = fmaf(w, __uint_as_float(v.z << 16), acc[4]);
        acc[5] = fmaf(w, __uint_as_float(v.z & 0xffff0000u), acc[5]);
        acc[6] = fmaf(w, __uint_as_float(v.w << 16), acc[6]);
        acc[7] = fmaf(w, __uint_as_float(v.w & 0xffff0000u), acc[7]);
    };

    if (slot == 0) {
        uint4 v = *(const uint4*)&X[(size_t)wid * ldx + cg * 8];
        fma_row(v, di * di);
    }
    const int e0 = row_ptr[wid], e1 = row_ptr[wid + 1];
    int e = e0 + slot;
    for (; e + 3 * SLOTS < e1; e += 4 * SLOTS) {
        const int2 d0 = edge_data[e];
        const int2 d1 = edge_data[e + SLOTS];
        const int2 d2 = edge_data[e + 2 * SLOTS];
        const int2 d3 = edge_data[e + 3 * SLOTS];
        const uint4 v0 = *(const uint4*)&X[(size_t)d0.x * ldx + cg * 8];
        const uint4 v1 = *(const uint4*)&X[(size_t)d1.x * ldx + cg * 8];
        const uint4 v2 = *(const uint4*)&X[(size_t)d2.x * ldx + cg * 8];
        const uint4 v3 = *(const uint4*)&X[(size_t)d3.x * ldx + cg * 8];
        fma_row(v0, di * __int_as_float(d0.y));
        fma_row(v1, di * __int_as_float(d1.y));
        fma_row(v2, di * __int_as_float(d2.y));
        fma_row(v3, di * __int_as_float(d3.y));
    }
    for (; e < e1; e += SLOTS) {
        const int2 d0 = edge_data[e];
        const uint4 v0 = *(const uint4*)&X[(size_t)d0.x * ldx + cg * 8];
        fma_row(v0, di * __int_as_float(d0.y));
    }
#pragma unroll
    for (int j = 0; j < 8; ++j) {
        if (SLOTS == 4) acc[j] += __shfl_xor(acc[j], 16);
        if (SLOTS >= 2) acc[j] += __shfl_xor(acc[j], 32);
    }
    if (slot == 0) {
        uint4 o;
        o.x = (uint)f2bf(acc[0]) | ((uint)f2bf(acc[1]) << 16);
        o.y = (uint)f2bf(acc[2]) | ((uint)f2bf(acc[3]) << 16);
        o.z = (uint)f2bf(acc[4]) | ((uint)f2bf(acc[5]) << 16);
        o.w = (uint)f2bf(acc[6]) | ((uint)f2bf(acc[7]) << 16);
        *(uint4*)&Y[(size_t)wid * ldy + cg * 8] = o;
    }
}

// ---------------------------------------------------------------------------
// bf16 MFMA GEMM, K=128. BM=128, BN=128, 256 threads. (layer-1 fused GEMM)
// Epilogue: cols 0:256 -> catA [N][256] (dense agg2 source, no h1 pollution),
//           cols 256:384 -> h1 [N][128].
// ---------------------------------------------------------------------------
__global__ __launch_bounds__(256)
void mfma_gemm_kernel(const ushort* __restrict__ A, int lda,
                      const ushort* __restrict__ Wt,
                      const float* __restrict__ bias,
                      ushort* __restrict__ catA, ushort* __restrict__ h1, int M) {
    __shared__ char Asmem[128 * 272];
    const int tid = threadIdx.x;
    const int lane = tid & 63;
    const int w = tid >> 6;
    const int rb = blockIdx.x * 128;
    const int cb = blockIdx.y * 128;

    {
        const int rowbase = tid >> 4;
        const int seg = tid & 15;
#pragma unroll
        for (int it = 0; it < 8; ++it) {
            int row = it * 16 + rowbase;
            uint4 v = make_uint4(0u, 0u, 0u, 0u);
            int r = rb + row;
            if (r < M) v = *(const uint4*)&A[(size_t)r * lda + seg * 8];
            *(uint4*)&Asmem[row * 272 + seg * 16] = v;
        }
    }
    __syncthreads();

    f32x4 acc[2][8];
#pragma unroll
    for (int i = 0; i < 2; ++i)
#pragma unroll
        for (int j = 0; j < 8; ++j) acc[i][j] = (f32x4){0.f, 0.f, 0.f, 0.f};

    const int arow0 = w * 32 + (lane & 15);
    const int kq = (lane >> 4) * 8;
    const int ccol = lane & 15;
#pragma unroll
    for (int ks = 0; ks < 4; ++ks) {
        const int k0 = ks * 32;
        const bf16x8 a0 = *(const bf16x8*)&Asmem[arow0 * 272 + (k0 + kq) * 2];
        const bf16x8 a1 = *(const bf16x8*)&Asmem[(arow0 + 16) * 272 + (k0 + kq) * 2];
#pragma unroll
        for (int ct = 0; ct < 8; ++ct) {
            const bf16x8 b = *(const bf16x8*)&Wt[(size_t)(cb + ct * 16 + ccol) * 128 + k0 + kq];
            acc[0][ct] = __builtin_amdgcn_mfma_f32_16x16x32_bf16(a0, b, acc[0][ct], 0, 0, 0);
            acc[1][ct] = __builtin_amdgcn_mfma_f32_16x16x32_bf16(a1, b, acc[1][ct], 0, 0, 0);
        }
    }

    const int rowq = (lane >> 4) * 4;
#pragma unroll
    for (int rt = 0; rt < 2; ++rt) {
#pragma unroll
        for (int ct = 0; ct < 8; ++ct) {
            const int col = cb + ct * 16 + ccol;
#pragma unroll
            for (int r = 0; r < 4; ++r) {
                const int row = rb + w * 32 + rt * 16 + rowq + r;
                if (row >= M) continue;
                float v = fmaxf(acc[rt][ct][r] + bias[col], 0.f);
                ushort bv = f2bf(v);
                if (col < 256) catA[(size_t)row * 256 + col] = bv;
                else           h1[(size_t)row * 128 + (col - 256)] = bv;
            }
        }
    }
}

// ---------------------------------------------------------------------------
// Fused layer-2 + attention + fc. 512 threads (8 waves) per 128-row tile.
// h1 is node-major [N][128].
// ---------------------------------------------------------------------------
__global__ __launch_bounds__(512, 4)
void gemm2fc_kernel(const ushort* __restrict__ bufB,
                    const ushort* __restrict__ Ws2t, const float* __restrict__ bs2,
                    const ushort* __restrict__ Wm22t, const float* __restrict__ bm22,
                    const ushort* __restrict__ h1buf,
                    const float* __restrict__ Watt, const float* __restrict__ batt,
                    const ushort* __restrict__ Wfct, const float* __restrict__ bfc,
                    float* __restrict__ Y, int M) {
    __shared__ __align__(16) char smem[69632];
    const int tid = threadIdx.x;
    const int rb = blockIdx.x * 128;

    {
        const int seg = tid & 15;
        const int rowbase = tid >> 4;
#pragma unroll
        for (int it = 0; it < 8; ++it) {
            int idx = it * 32 + rowbase;
            int region = idx >> 7;
            int row = idx & 127;
            int r = rb + row;
            uint4 v = make_uint4(0u, 0u, 0u, 0u);
            if (r < M) v = *(const uint4*)&bufB[(size_t)r * 256 + region * 128 + seg * 8];
            *(uint4*)&smem[region * 34816 + row * 272 + seg * 16] = v;
        }
    }
    __syncthreads();

    const int w = tid >> 6;
    const int lane = tid & 63;
    const int branch = w >> 2;
    const int wl = w & 3;
    const char* Areg = smem + branch * 34816;
    const ushort* Wt = branch ? Wm22t : Ws2t;
    const float* bias = branch ? bm22 : bs2;

    f32x4 acc[2][8];
#pragma unroll
    for (int i = 0; i < 2; ++i)
#pragma unroll
        for (int j = 0; j < 8; ++j) acc[i][j] = (f32x4){0.f, 0.f, 0.f, 0.f};

    const int arow0 = wl * 32 + (lane & 15);
    const int kq = (lane >> 4) * 8;
    const int ccol = lane & 15;
#pragma unroll
    for (int ks = 0; ks < 4; ++ks) {
        const int k0 = ks * 32;
        const bf16x8 a0 = *(const bf16x8*)&Areg[arow0 * 272 + (k0 + kq) * 2];
        const bf16x8 a1 = *(const bf16x8*)&Areg[(arow0 + 16) * 272 + (k0 + kq) * 2];
#pragma unroll
        for (int ct = 0; ct < 8; ++ct) {
            const bf16x8 b = *(const bf16x8*)&Wt[(size_t)(ct * 16 + ccol) * 128 + k0 + kq];
            acc[0][ct] = __builtin_amdgcn_mfma_f32_16x16x32_bf16(a0, b, acc[0][ct], 0, 0, 0);
            acc[1][ct] = __builtin_amdgcn_mfma_f32_16x16x32_bf16(a1, b, acc[1][ct], 0, 0, 0);
        }
    }

#pragma unroll
    for (int rt = 0; rt < 2; ++rt)
#pragma unroll
        for (int ct = 0; ct < 8; ++ct) {
            const float bcol = bias[ct * 16 + ccol];
#pragma unroll
            for (int r = 0; r < 4; ++r)
                acc[rt][ct][r] = fmaxf(acc[rt][ct][r] + bcol, 0.f);
        }

    const int quad = lane >> 4;
    if (branch == 1) {
        float wv[8];
#pragma unroll
        for (int ct = 0; ct < 8; ++ct) wv[ct] = Watt[ct * 16 + ccol];
        const float ba = batt[0];
#pragma unroll
        for (int rt = 0; rt < 2; ++rt) {
#pragma unroll
            for (int r = 0; r < 4; ++r) {
                const int row0 = rb + wl * 32 + rt * 16 + quad * 4 + r;
                const int rowc = (row0 < M) ? row0 : (M - 1);
                const ushort* h1row = &h1buf[(size_t)rowc * 128];
                float bp = 0.f, ap = 0.f;
#pragma unroll
                for (int ct = 0; ct < 8; ++ct) {
                    bp += acc[rt][ct][r] * wv[ct];
                    ap += bf2f(h1row[ct * 16 + ccol]) * wv[ct];
                }
#pragma unroll
                for (int off = 1; off < 16; off <<= 1) {
                    bp += __shfl_xor(bp, off);
                    ap += __shfl_xor(ap, off);
                }
                const float a = ap + ba, b = bp + ba;
                const float m = fmaxf(a, b);
                const float ea = __expf(a - m), eb = __expf(b - m);
                const float inv = 1.f / (ea + eb);
                const float wa = ea * inv, wb = eb * inv;
#pragma unroll
                for (int ct = 0; ct < 8; ++ct) {
                    const float h1 = bf2f(h1row[ct * 16 + ccol]);
                    acc[rt][ct][r] = fmaf(wa, h1, wb * acc[rt][ct][r]);
                }
            }
        }
    }
    __syncthreads();

#pragma unroll
    for (int rt = 0; rt < 2; ++rt) {
#pragma unroll
        for (int ct = 0; ct < 8; ++ct) {
            const int col = branch * 128 + ct * 16 + ccol;
#pragma unroll
            for (int r = 0; r < 4; ++r) {
                const int row = wl * 32 + rt * 16 + quad * 4 + r;
                *(ushort*)&smem[row * 528 + col * 2] = f2bf(acc[rt][ct][r]);
            }
        }
    }
    __syncthreads();

    f32x4 fcacc[4];
#pragma unroll
    for (int j = 0; j < 4; ++j) fcacc[j] = (f32x4){0.f, 0.f, 0.f, 0.f};
    const int frow = w * 16 + (lane & 15);
#pragma unroll
    for (int ks = 0; ks < 8; ++ks) {
        const int k0 = ks * 32;
        const bf16x8 a = *(const bf16x8*)&smem[frow * 528 + (k0 + kq) * 2];
#pragma unroll
        for (int ct = 0; ct < 4; ++ct) {
            const bf16x8 b = *(const bf16x8*)&Wfct[(size_t)(ct * 16 + ccol) * 256 + k0 + kq];
            fcacc[ct] = __builtin_amdgcn_mfma_f32_16x16x32_bf16(a, b, fcacc[ct], 0, 0, 0);
        }
    }
#pragma unroll
    for (int ct = 0; ct < 4; ++ct) {
        const int col = ct * 16 + ccol;
        const float bcol = bfc[col];
#pragma unroll
        for (int r = 0; r < 4; ++r) {
            const int row = rb + w * 16 + quad * 4 + r;
            if (row < M) Y[(size_t)row * 64 + col] = fcacc[ct][r] + bcol;
        }
    }
}

// ---------------------------------------------------------------------------
extern "C" void kernel_launch(void* const* d_in, const int* in_sizes, int n_in,
                              void* d_out, int out_size, void* d_ws, size_t ws_size,
                              hipStream_t stream) {
    const int N = N_NODES, E = N_EDGES;
    const float* x     = (const float*)d_in[0];
    const int*   ei    = (const int*)d_in[1];
    const int*   esrc  = ei;
    const int*   edst  = ei + E;
    const float* W_s1  = (const float*)d_in[2];
    const float* b_s1  = (const float*)d_in[3];
    const float* W_s2  = (const float*)d_in[4];
    const float* b_s2  = (const float*)d_in[5];
    const float* W_m1  = (const float*)d_in[6];
    const float* b_m1  = (const float*)d_in[7];
    const float* W_m21 = (const float*)d_in[8];
    const float* b_m21 = (const float*)d_in[9];
    const float* W_m22 = (const float*)d_in[10];
    const float* b_m22 = (const float*)d_in[11];
    const float* W_att = (const float*)d_in[12];
    const float* b_att = (const float*)d_in[13];
    const float* W_fc  = (const float*)d_in[14];
    const float* b_fc  = (const float*)d_in[15];
    float* out = (float*)d_out;

    char* base = (char*)d_ws;
    size_t off = 0;
    auto take = [&](size_t nbytes) -> void* {
        void* p = base + off;
        off += (nbytes + 255) & ~(size_t)255;
        return p;
    };
    int*    hist      = (int*)take((size_t)N * 4);
    int*    row_ptr   = (int*)take((size_t)(N + 1) * 4);
    int*    bsum      = (int*)take((size_t)SCAN_NB * 4);
    int*    rank      = (int*)take((size_t)E * 4);
    int2*   edge_data = (int2*)take((size_t)E * 8);
    float*  dinv      = (float*)take((size_t)N * 4);
    ushort* xb        = (ushort*)take((size_t)N * 128 * 2);
    ushort* agg_x     = (ushort*)take((size_t)N * 128 * 2);
    ushort* catA      = (ushort*)take((size_t)N * 256 * 2);   // [h_s1 | h2a], dense
    ushort* h1buf     = (ushort*)take((size_t)N * 128 * 2);   // h1, node-major
    ushort* bufB      = (ushort*)take((size_t)N * 256 * 2);
    ushort* Wcat_t    = (ushort*)take((size_t)384 * 128 * 2);
    ushort* Ws2_t     = (ushort*)take((size_t)128 * 128 * 2);
    ushort* Wm22_t    = (ushort*)take((size_t)128 * 128 * 2);
    ushort* Wfc_t     = (ushort*)take((size_t)64 * 256 * 2);
    float*  bcat      = (float*)take((size_t)384 * 4);

    // 1. zero hist
    hipMemsetAsync(hist, 0, (size_t)N * 4, stream);
    // 2. fused prep (cvt | degree+rank | packs)
    prep_kernel<<<PREP_NB, 256, 0, stream>>>(x, (uint2*)xb, edst, hist, rank,
                                             W_s1, W_m21, W_m1, b_s1, b_m21, b_m1,
                                             Wcat_t, bcat, W_s2, Ws2_t, W_m22, Wm22_t,
                                             W_fc, Wfc_t, row_ptr);
    // 3-4. scan
    scan1_kernel<<<SCAN_NB, SCAN_BS, 0, stream>>>(hist, bsum, dinv, N);
    scan3_kernel<<<SCAN_NB, SCAN_BS, 0, stream>>>(hist, bsum, row_ptr, N);
    // 5. fill CSR (atomic-free)
    fill_kernel<<<(E + 255) / 256, 256, 0, stream>>>(esrc, edst, E, row_ptr, rank,
                                                     edge_data, dinv);

    // 6. layer-1 aggregation
    agg_bf16<128><<<(N + 3) / 4, 256, 0, stream>>>(xb, 128, agg_x, 128, row_ptr, edge_data, dinv, N);
    // 7. fused layer-1 GEMM -> catA + h1
    dim3 gm384((N + 127) / 128, 3);
    mfma_gemm_kernel<<<gm384, 256, 0, stream>>>(agg_x, 128, Wcat_t, bcat, catA, h1buf, N);
    // 8. layer-2 aggregation of [h_s1 | h2a] (dense 512B rows)
    agg_bf16<256><<<(N + 3) / 4, 256, 0, stream>>>(catA, 256, bufB, 256, row_ptr, edge_data, dinv, N);
    // 9. fused layer-2 GEMMs + attention + fc -> d_out
    gemm2fc_kernel<<<(N + 127) / 128, 512, 0, stream>>>(bufB, Ws2_t, b_s2, Wm22_t, b_m22,
                                                        h1buf, W_att, b_att, Wfc_t, b_fc, out, N);
}